// Round 19
// baseline (39.968 us; speedup 1.0000x reference)
//
#include <hip/hip_runtime.h>
#include <hip/hip_bf16.h>
#include <hip/hip_fp8.h>

// ContrastiveLoss fused kernel for MI355X (gfx950).
//
// Math reduction (T=0.5):
//   f = x / max(||x||, 1e-8)   (rows)
//   s_ij = f_i . f_j
//   den_i = sum_{j: label_j != label_i} exp(2 s_ij)
//   loss  = sum_i [ c_i * log(den_i) - sum_{j same label, j != i} 2 s_ij ]
//           / (sum_i c_i + 1e-5),   c_i = count(label_i) - 1
//
// N=4096, D=512, labels in [0,100).
//
// Round 19: ZERO GLOBAL ATOMICS in k2 (privatized partials). R14-R18
// triangulation: boundaries are cheap; k2 is ~28 us with only ~7 us of
// pipe work (R16: Mfma 6.8% + VALU 9%) -> waves are waiting. The one
// element unchanged since R1: ~524k same-address-contended f32 atomic
// RMWs on den/pos (64 serialized L2 round-trips per element). Fix:
// each (row i, tile-slot s) has exactly ONE writer block (row-path if
// s >= t(i), col-path if s < t(i)), so k2 writes PLAIN STORES into
// den_p/pos_p[4096][32] (1 MB, no init needed, no contention). k3a
// sums 32 contiguous slots/row (coalesced, trivial). Everything else
// bit-identical to R17 (best, 36.74 us): fp8 e4m3 16x16x32, 8-wave
// 512-thread blocks, whole 64 KB B tile staged once, ONE syncthreads,
// zero-barrier main loop, symmetric 528 tile-pairs.

typedef float floatx4 __attribute__((ext_vector_type(4)));
typedef long lng2 __attribute__((ext_vector_type(2)));
typedef unsigned int u32;
typedef unsigned char u8;

#define N_ROWS 4096
#define DIM 512
#define GRPB 8192              // bytes per 16-row fp8 fragment group (16*512)
#define EPS_NORM 1e-8f
#define EPS_DEN 1e-5f
#define TI 128                 // tile size (rows and cols)
#define NT (N_ROWS / TI)       // 32 tiles
#define NPAIR (NT * (NT + 1) / 2)   // 528 blocks
#define NSLAB 8                // 8 slabs of 16 j-rows per tile

static __device__ inline void load_lds16(const char* g, char* l) {
  __builtin_amdgcn_global_load_lds(
      (const __attribute__((address_space(1))) void*)g,
      (__attribute__((address_space(3))) void*)l, 16, 0, 0);
}

// wave-per-row normalize + fp8 pack, fragment-major store; grid 1024 x 256.
// G layout (fp8): group g = row>>4 (8192 B), kt-pair p = kt>>1 (1024 B);
// consumer lane l = kq*16 + (row&15) holds fragment of kt at byte
// l*16 + (kt&1)*8, covering k = kt*32 + kq*8 .. +8.
__global__ void k1_normalize(const float* __restrict__ x,
                             const int* __restrict__ labels,
                             u8* __restrict__ G, u8* __restrict__ lab8,
                             float* __restrict__ acc2, int* __restrict__ done) {
  const int row = blockIdx.x * 4 + (threadIdx.x >> 6);
  const int lane = threadIdx.x & 63;
  const float4* src = reinterpret_cast<const float4*>(x + (size_t)row * DIM);
  float4 v0 = src[lane * 2];
  float4 v1 = src[lane * 2 + 1];
  float ss = v0.x*v0.x + v0.y*v0.y + v0.z*v0.z + v0.w*v0.w
           + v1.x*v1.x + v1.y*v1.y + v1.z*v1.z + v1.w*v1.w;
#pragma unroll
  for (int m = 1; m < 64; m <<= 1) ss += __shfl_xor(ss, m, 64);
  float scale = 1.f / fmaxf(sqrtf(ss), EPS_NORM);

  u32 lo = ((u32)__hip_fp8_e4m3(v0.x * scale).__x)
         | ((u32)__hip_fp8_e4m3(v0.y * scale).__x << 8)
         | ((u32)__hip_fp8_e4m3(v0.z * scale).__x << 16)
         | ((u32)__hip_fp8_e4m3(v0.w * scale).__x << 24);
  u32 hi = ((u32)__hip_fp8_e4m3(v1.x * scale).__x)
         | ((u32)__hip_fp8_e4m3(v1.y * scale).__x << 8)
         | ((u32)__hip_fp8_e4m3(v1.z * scale).__x << 16)
         | ((u32)__hip_fp8_e4m3(v1.w * scale).__x << 24);
  uint2 o; o.x = lo; o.y = hi;

  const int kt = lane >> 2;
  const int kq = lane & 3;
  char* dst = (char*)G + (size_t)(row >> 4) * GRPB + (kt >> 1) * 1024
            + (kq * 16 + (row & 15)) * 16 + (kt & 1) * 8;
  *reinterpret_cast<uint2*>(dst) = o;

  if (lane == 1) lab8[row] = (u8)labels[row];
  if (blockIdx.x == 0 && threadIdx.x == 0) {
    acc2[0] = 0.f; acc2[1] = 0.f; done[0] = 0;
  }
}

// fused fp8 sim-GEMM + symmetric reduction into PRIVATIZED partial slots.
// 512 threads = 8 waves; whole 64 KB B tile staged once; zero-barrier loop.
__global__ __launch_bounds__(512, 4) void k2_fused(
    const u8* __restrict__ G, const u8* __restrict__ lab8,
    float* __restrict__ den_p, float* __restrict__ pos_p) {
  __shared__ u8 Bsh[64 * 1024];          // whole B tile: 64 chunks x 1 KB
  __shared__ int labj_sh[TI];
  __shared__ float colden[TI], colpos[TI];

  const char* Gb = (const char*)G;
  char* bshb = (char*)Bsh;

  // decode pair (ti, tj), ti <= tj, from blockIdx
  int b = blockIdx.x;
  int ti = 0, rem = NT;
  while (b >= rem) { b -= rem; ++ti; --rem; }
  const int tj = ti + b;
  const bool diag = (ti == tj);

  const int tid = threadIdx.x;
  const int wv = tid >> 6;                // 0..7
  const int lane = tid & 63;
  const int l15 = lane & 15;
  const int kg4 = lane >> 4;              // 0..3 (16-col groups)

  const int ib = ti * TI;
  const int jb = tj * TI;

  // stage the WHOLE B tile (64 KB = 64 chunks); wave wv stages chunks
  // wv*8 .. wv*8+7. Contiguous 1 KB src AND dst.
#pragma unroll
  for (int c = 0; c < 8; ++c) {
    const int chunk = wv * 8 + c;
    load_lds16(Gb + (size_t)(tj * 8 + (chunk >> 3)) * GRPB
                  + (chunk & 7) * 1024 + lane * 16,
               bshb + chunk * 1024 + lane * 16);
  }
  if (tid < TI) {
    labj_sh[tid] = lab8[jb + tid];
    colden[tid] = 0.f;
    colpos[tid] = 0.f;
  }

  // A fragments: 16 rows/wave = 1 fp8 fragment group -> 32 VGPRs.
  long a[16];
  {
    const char* ab = Gb + (size_t)(ti * 8 + wv) * GRPB + lane * 16;
#pragma unroll
    for (int q = 0; q < 8; ++q) {
      lng2 v = *reinterpret_cast<const lng2*>(ab + q * 1024);
      a[2 * q] = v.x; a[2 * q + 1] = v.y;
    }
  }
  // pin A in VGPRs (round-1 pathology: compiler sank loads into the loop)
#pragma unroll
  for (int kt = 0; kt < 16; ++kt)
    asm volatile("" : "+v"(a[kt]));

  // C/D layout (verified gfx950, dtype-independent): col = lane&15 (j),
  // row = kg4*4 + r (i). lane's 4 output rows: i_base + r.
  const int i_base = ib + wv * 16 + kg4 * 4;
  const u32 labp = *reinterpret_cast<const u32*>(lab8 + i_base);

  float den_acc[4] = {0.f, 0.f, 0.f, 0.f};
  float pos_acc[4] = {0.f, 0.f, 0.f, 0.f};

  __syncthreads();   // ONE drain: whole tile staged, labels + col accs ready

  // barrier-free main loop: 8 slabs; per slab two 8-deep MFMA chains
#pragma unroll
  for (int t = 0; t < NSLAB; ++t) {
    const int jrow = jb + t * 16 + l15;
    const int labj = labj_sh[t * 16 + l15];

    floatx4 acc_a = {0.f,0.f,0.f,0.f};
    floatx4 acc_b = {0.f,0.f,0.f,0.f};
    const char* bbase = bshb + t * 8192 + lane * 16;
#pragma unroll
    for (int q = 0; q < 8; ++q) {
      lng2 b2 = *reinterpret_cast<const lng2*>(bbase + q * 1024);
      acc_a = __builtin_amdgcn_mfma_f32_16x16x32_fp8_fp8(a[2*q],   b2.x, acc_a, 0, 0, 0);
      acc_b = __builtin_amdgcn_mfma_f32_16x16x32_fp8_fp8(a[2*q+1], b2.y, acc_b, 0, 0, 0);
    }

    float cd = 0.f, cp = 0.f;   // col partials for this 16-j slab
#pragma unroll
    for (int r = 0; r < 4; ++r) {
      const int labi = (int)((labp >> (8 * r)) & 255u);
      const int irow = i_base + r;
      float s2 = 2.f * (acc_a[r] + acc_b[r]);
      float e = __expf(s2);
      bool sm = (labj == labi);
      float dv = sm ? 0.f : e;
      float pv = (sm && (jrow != irow)) ? s2 : 0.f;
      den_acc[r] += dv;
      pos_acc[r] += pv;
      cd += dv; cp += pv;
    }
    if (!diag) {
      // reduce col partials across the 4 kg groups (lanes sharing l15)
      cd += __shfl_xor(cd, 16, 64); cd += __shfl_xor(cd, 32, 64);
      cp += __shfl_xor(cp, 16, 64); cp += __shfl_xor(cp, 32, 64);
      if (kg4 == 0) {
        atomicAdd(&colden[t * 16 + l15], cd);   // LDS-scope, cheap
        atomicAdd(&colpos[t * 16 + l15], cp);
      }
    }
  }

  // row path: reduce across 16 cols (lanes with same kg4), then ONE plain
  // store per row into private slot (i, tj) -- no contention by design.
#pragma unroll
  for (int r = 0; r < 4; ++r) {
    float dd = den_acc[r], pp = pos_acc[r];
#pragma unroll
    for (int m = 1; m < 16; m <<= 1) {
      dd += __shfl_xor(dd, m, 64);
      pp += __shfl_xor(pp, m, 64);
    }
    if (l15 == 0) {
      den_p[(size_t)(i_base + r) * NT + tj] = dd;
      pos_p[(size_t)(i_base + r) * NT + tj] = pp;
    }
  }

  // col path flush (off-diagonal): plain store into slot (j, ti)
  if (!diag) {
    __syncthreads();   // all waves' LDS col atomics done
    if (tid < TI) {
      den_p[(size_t)(jb + tid) * NT + ti] = colden[tid];
      pos_p[(size_t)(jb + tid) * NT + ti] = colpos[tid];
    }
  }
}

// per-row finalize: sum 32 private slots/row (coalesced), then scalar.
// 16 blocks x 256 threads; last-done block writes out (proven protocol).
__global__ void k3a(const float* __restrict__ den_p, const float* __restrict__ pos_p,
                    const int* __restrict__ labels, float* __restrict__ acc2,
                    int* __restrict__ done, float* __restrict__ out) {
  __shared__ int hist[128];
  __shared__ float sn[4], sz[4];
  const int tid = threadIdx.x;
  if (tid < 128) hist[tid] = 0;
  __syncthreads();
  for (int i = tid; i < N_ROWS; i += 256) atomicAdd(&hist[labels[i]], 1);
  __syncthreads();

  const int row = blockIdx.x * 256 + tid;
  float dv = 0.f, pv = 0.f;
  const float4* dp = reinterpret_cast<const float4*>(den_p + (size_t)row * NT);
  const float4* pp = reinterpret_cast<const float4*>(pos_p + (size_t)row * NT);
#pragma unroll
  for (int q = 0; q < NT / 4; ++q) {
    float4 d4 = dp[q];
    float4 p4 = pp[q];
    dv += d4.x + d4.y + d4.z + d4.w;
    pv += p4.x + p4.y + p4.z + p4.w;
  }

  int c = hist[labels[row]] - 1;
  float num = (float)c * logf(dv) - pv;
  float nnz = (float)c;
#pragma unroll
  for (int m = 1; m < 64; m <<= 1) {
    num += __shfl_xor(num, m, 64);
    nnz += __shfl_xor(nnz, m, 64);
  }
  if ((tid & 63) == 0) { sn[tid >> 6] = num; sz[tid >> 6] = nnz; }
  __syncthreads();
  if (tid == 0) {
    atomicAdd(&acc2[0], sn[0] + sn[1] + sn[2] + sn[3]);
    atomicAdd(&acc2[1], sz[0] + sz[1] + sz[2] + sz[3]);
    __threadfence();
    int old = atomicAdd(done, 1);
    if (old == 15) {
      float tn = atomicAdd(&acc2[0], 0.f);   // coherent device-scope read
      float tz = atomicAdd(&acc2[1], 0.f);
      out[0] = tn / (tz + EPS_DEN);
    }
  }
}

extern "C" void kernel_launch(void* const* d_in, const int* in_sizes, int n_in,
                              void* d_out, int out_size, void* d_ws, size_t ws_size,
                              hipStream_t stream) {
  const float* x = (const float*)d_in[0];
  const int* labels = (const int*)d_in[1];

  // ws: G fp8 (2MB) | den_p f32[4096*32] (512KB) | pos_p (512KB)
  //   | lab8 u8[4096] | acc2 f32[2] | done i32[1]
  u8* G = (u8*)d_ws;
  float* den_p = (float*)((char*)d_ws + (size_t)N_ROWS * DIM);
  float* pos_p = den_p + (size_t)N_ROWS * NT;
  u8* lab8 = (u8*)(pos_p + (size_t)N_ROWS * NT);
  float* acc2 = (float*)(lab8 + N_ROWS);
  int* done = (int*)(acc2 + 2);
  float* out = (float*)d_out;

  hipLaunchKernelGGL(k1_normalize, dim3(N_ROWS / 4), dim3(256), 0, stream,
                     x, labels, G, lab8, acc2, done);
  hipLaunchKernelGGL(k2_fused, dim3(NPAIR), dim3(512), 0, stream,
                     G, lab8, den_p, pos_p);
  hipLaunchKernelGGL(k3a, dim3(16), dim3(256), 0, stream,
                     den_p, pos_p, labels, acc2, done, out);
}